// Round 1
// baseline (329.235 us; speedup 1.0000x reference)
//
#include <hip/hip_runtime.h>

// ---------------- problem constants ----------------
#define CIN    96
#define COUT   192
#define HIN    56
#define HOUT   28
#define NBATCH 64
#define NPIX   (NBATCH*HOUT*HOUT)   // 50176
#define K1     (CIN*9)              // 864
#define K2     (COUT*9)             // 1728
#define KS     CIN                  // 96
#define PH     30                   // padded act H/W
#define EPSBN  1e-5f

// ---------------- ws layout (bytes) ----------------
#define W1B_OFF 0u           // bf16 192*864   -> 331776 B
#define W2B_OFF 331776u      // bf16 192*1728  -> 663552 B
#define WSB_OFF 995328u      // bf16 192*96    -> 36864 B
#define S1_OFF  1032192u
#define S2_OFF  1032960u
#define SS_OFF  1033728u
#define B1_OFF  1034496u
#define B2_OFF  1035264u
#define BS_OFF  1036032u
#define ACT_OFF 1048576u     // bf16 64*192*30*30 -> 22118400 B
#define ACT_BYTES 22118400u
#define SC_OFF  23166976u    // f32 9633792 -> 38535168 B

typedef __attribute__((ext_vector_type(8))) short bf16x8;
typedef __attribute__((ext_vector_type(4))) float f32x4;

__device__ __forceinline__ short f2bf(float f) {
    unsigned u = __float_as_uint(f);
    u += 0x7fffu + ((u >> 16) & 1u);
    return (short)(u >> 16);
}

// swizzled LDS index (shorts): tile [64 rows][32 k], 16B-slot XOR on (row>>1)&3
__device__ __forceinline__ int lidx(int row, int slot) {
    return row * 32 + ((slot ^ ((row >> 1) & 3)) << 3);
}

__device__ __forceinline__ float rational_eval(float v, const float* nm, const float* dn) {
    float p = nm[5];
    p = p * v + nm[4];
    p = p * v + nm[3];
    p = p * v + nm[2];
    p = p * v + nm[1];
    p = p * v + nm[0];
    float xa = fabsf(v);
    float q = 1.0f;
    float pw = xa;
    q += dn[0] * pw; pw *= xa;
    q += dn[1] * pw; pw *= xa;
    q += dn[2] * pw; pw *= xa;
    q += dn[3] * pw;
    float inv = __builtin_amdgcn_rcpf(q);
    inv = inv * (2.0f - q * inv);   // one Newton step; q >= 1 so well-behaved
    return p * inv;
}

// ---------------- prep kernels ----------------
extern "C" __global__ void prep_scales_kernel(
    const float* g1, const float* b1, const float* m1, const float* v1,
    const float* g2, const float* b2, const float* m2, const float* v2,
    const float* gs, const float* bs, const float* ms, const float* vs,
    float* s1, float* s2, float* ss, float* bias1, float* bias2, float* biass)
{
    int i = threadIdx.x;
    if (i < COUT) {
        float a1 = g1[i] * rsqrtf(v1[i] + EPSBN); s1[i] = a1; bias1[i] = b1[i] - m1[i] * a1;
        float a2 = g2[i] * rsqrtf(v2[i] + EPSBN); s2[i] = a2; bias2[i] = b2[i] - m2[i] * a2;
        float a3 = gs[i] * rsqrtf(vs[i] + EPSBN); ss[i] = a3; biass[i] = bs[i] - ms[i] * a3;
    }
}

extern "C" __global__ void prep_w_kernel(const float* __restrict__ w, const float* __restrict__ s,
                                         short* __restrict__ wb, int K, int total)
{
    int i = blockIdx.x * 256 + threadIdx.x;
    if (i < total) {
        int co = i / K;
        wb[i] = f2bf(w[i] * s[co]);
    }
}

// ---------------- kernel A: conv1 + BN1 + rational -> padded bf16 act; shortcut + BNs -> f32 sc ----------------
extern "C" __global__ __launch_bounds__(256)
void convA_kernel(const float* __restrict__ x,
                  const short* __restrict__ w1b,
                  const short* __restrict__ wsb,
                  const float* __restrict__ bias1,
                  const float* __restrict__ biass,
                  const float* __restrict__ num_r, const float* __restrict__ den_r,
                  const float* __restrict__ num_g, const float* __restrict__ den_g,
                  const float* __restrict__ num_b, const float* __restrict__ den_b,
                  short* __restrict__ act, float* __restrict__ sc)
{
    __shared__ short lA[64 * 32];
    __shared__ short lB[64 * 32];

    const int tid  = threadIdx.x;
    const int lane = tid & 63;
    const int wave = tid >> 6;
    const int wr = wave >> 1, wc = wave & 1;
    const int bco = blockIdx.x % 3;
    const int bp  = blockIdx.x / 3;
    const int co0 = bco * 64, p0 = bp * 64;

    // staging coords: thread -> (row 0..63, 16B slot 0..3)
    const int trow  = tid >> 2;
    const int tslot = tid & 3;
    const int p    = p0 + trow;
    const int n    = p / 784;
    const int prem = p - n * 784;
    const int oh   = prem / 28;
    const int ow   = prem - oh * 28;
    const int xbase = n * (CIN * HIN * HIN);
    const int ih0 = 2 * oh - 1;
    const int iw0 = 2 * ow - 1;
    const int ldsW = trow * 32 + ((tslot ^ ((trow >> 1) & 3)) << 3);

    // rational coeffs into registers (den pre-abs'd)
    float c_nm[3][6], c_dn[3][4];
#pragma unroll
    for (int i = 0; i < 6; i++) { c_nm[0][i] = num_r[i]; c_nm[1][i] = num_g[i]; c_nm[2][i] = num_b[i]; }
#pragma unroll
    for (int i = 0; i < 4; i++) { c_dn[0][i] = fabsf(den_r[i]); c_dn[1][i] = fabsf(den_g[i]); c_dn[2][i] = fabsf(den_b[i]); }

    f32x4 acc[2][2];
#pragma unroll
    for (int m = 0; m < 2; m++)
#pragma unroll
        for (int nn = 0; nn < 2; nn++) acc[m][nn] = (f32x4){0.f, 0.f, 0.f, 0.f};

    // ---------- main conv1 K-loop ----------
    for (int k0 = 0; k0 < K1; k0 += 32) {
        bf16x8 av = *(const bf16x8*)&w1b[(co0 + trow) * K1 + k0 + tslot * 8];
        bf16x8 bv;
#pragma unroll
        for (int j = 0; j < 8; j++) {
            int k  = k0 + tslot * 8 + j;
            int ci = k / 9;
            int r9 = k - ci * 9;
            int kh = r9 / 3;
            int kw = r9 - kh * 3;
            int ih = ih0 + kh, iw = iw0 + kw;
            float v = 0.f;
            if ((unsigned)ih < 56u && (unsigned)iw < 56u)
                v = x[xbase + ci * 3136 + ih * 56 + iw];
            bv[j] = f2bf(v);
        }
        *(bf16x8*)&lA[ldsW] = av;
        *(bf16x8*)&lB[ldsW] = bv;
        __syncthreads();

        const int ksl = lane >> 4;
        bf16x8 af[2], bfr[2];
#pragma unroll
        for (int m = 0; m < 2; m++) {
            int rr = wr * 32 + m * 16 + (lane & 15);
            af[m] = *(const bf16x8*)&lA[lidx(rr, ksl)];
        }
#pragma unroll
        for (int nn = 0; nn < 2; nn++) {
            int rc = wc * 32 + nn * 16 + (lane & 15);
            bfr[nn] = *(const bf16x8*)&lB[lidx(rc, ksl)];
        }
#pragma unroll
        for (int m = 0; m < 2; m++)
#pragma unroll
            for (int nn = 0; nn < 2; nn++)
                acc[m][nn] = __builtin_amdgcn_mfma_f32_16x16x32_bf16(af[m], bfr[nn], acc[m][nn], 0, 0, 0);
        __syncthreads();
    }

    // ---------- shortcut 1x1 s2 GEMM (K=96) ----------
    f32x4 sacc[2][2];
#pragma unroll
    for (int m = 0; m < 2; m++)
#pragma unroll
        for (int nn = 0; nn < 2; nn++) sacc[m][nn] = (f32x4){0.f, 0.f, 0.f, 0.f};

    const int xcenter = xbase + (2 * oh) * 56 + (2 * ow);
    for (int c0 = 0; c0 < KS; c0 += 32) {
        bf16x8 av = *(const bf16x8*)&wsb[(co0 + trow) * KS + c0 + tslot * 8];
        bf16x8 bv;
#pragma unroll
        for (int j = 0; j < 8; j++) {
            int ci = c0 + tslot * 8 + j;
            bv[j] = f2bf(x[xcenter + ci * 3136]);
        }
        *(bf16x8*)&lA[ldsW] = av;
        *(bf16x8*)&lB[ldsW] = bv;
        __syncthreads();

        const int ksl = lane >> 4;
        bf16x8 af[2], bfr[2];
#pragma unroll
        for (int m = 0; m < 2; m++) {
            int rr = wr * 32 + m * 16 + (lane & 15);
            af[m] = *(const bf16x8*)&lA[lidx(rr, ksl)];
        }
#pragma unroll
        for (int nn = 0; nn < 2; nn++) {
            int rc = wc * 32 + nn * 16 + (lane & 15);
            bfr[nn] = *(const bf16x8*)&lB[lidx(rc, ksl)];
        }
#pragma unroll
        for (int m = 0; m < 2; m++)
#pragma unroll
            for (int nn = 0; nn < 2; nn++)
                sacc[m][nn] = __builtin_amdgcn_mfma_f32_16x16x32_bf16(af[m], bfr[nn], sacc[m][nn], 0, 0, 0);
        __syncthreads();
    }

    // ---------- epilogue: bias + rational -> act(bf16 padded); bias -> sc(f32) ----------
#pragma unroll
    for (int nn = 0; nn < 2; nn++) {
        const int pp  = p0 + wc * 32 + nn * 16 + (lane & 15);
        const int n2  = pp / 784;
        const int r2  = pp - n2 * 784;
        const int oh2 = r2 / 28;
        const int ow2 = r2 - oh2 * 28;
        const int abase = n2 * (COUT * PH * PH) + (oh2 + 1) * PH + (ow2 + 1);
        const int obase = n2 * (COUT * 784) + oh2 * 28 + ow2;
#pragma unroll
        for (int m = 0; m < 2; m++) {
#pragma unroll
            for (int r = 0; r < 4; r++) {
                const int co = co0 + wr * 32 + m * 16 + ((lane >> 4) << 2) + r;
                const int var3 = co % 3;
                float nm[6], dn[4];
#pragma unroll
                for (int i = 0; i < 6; i++) nm[i] = (var3 == 0) ? c_nm[0][i] : ((var3 == 1) ? c_nm[1][i] : c_nm[2][i]);
#pragma unroll
                for (int i = 0; i < 4; i++) dn[i] = (var3 == 0) ? c_dn[0][i] : ((var3 == 1) ? c_dn[1][i] : c_dn[2][i]);
                float v = acc[m][nn][r] + bias1[co];
                float a = rational_eval(v, nm, dn);
                act[abase + co * (PH * PH)] = f2bf(a);
                float sv = sacc[m][nn][r] + biass[co];
                sc[obase + co * 784] = sv;
            }
        }
    }
}

// ---------------- kernel B: conv2 + BN2 + shortcut add + rational -> out(f32) ----------------
extern "C" __global__ __launch_bounds__(256)
void convB_kernel(const short* __restrict__ act,
                  const short* __restrict__ w2b,
                  const float* __restrict__ bias2,
                  const float* __restrict__ sc,
                  const float* __restrict__ num_r, const float* __restrict__ den_r,
                  const float* __restrict__ num_g, const float* __restrict__ den_g,
                  const float* __restrict__ num_b, const float* __restrict__ den_b,
                  float* __restrict__ out)
{
    __shared__ short lA[64 * 32];
    __shared__ short lB[64 * 32];

    const int tid  = threadIdx.x;
    const int lane = tid & 63;
    const int wave = tid >> 6;
    const int wr = wave >> 1, wc = wave & 1;
    const int bco = blockIdx.x % 3;
    const int bp  = blockIdx.x / 3;
    const int co0 = bco * 64, p0 = bp * 64;

    const int trow  = tid >> 2;
    const int tslot = tid & 3;
    const int p    = p0 + trow;
    const int n    = p / 784;
    const int prem = p - n * 784;
    const int oh   = prem / 28;
    const int ow   = prem - oh * 28;
    const int abase = n * (COUT * PH * PH) + oh * PH + ow;   // (kh,kw) add (kh*30+kw); pad ring handles borders
    const int ldsW = trow * 32 + ((tslot ^ ((trow >> 1) & 3)) << 3);

    float c_nm[3][6], c_dn[3][4];
#pragma unroll
    for (int i = 0; i < 6; i++) { c_nm[0][i] = num_r[i]; c_nm[1][i] = num_g[i]; c_nm[2][i] = num_b[i]; }
#pragma unroll
    for (int i = 0; i < 4; i++) { c_dn[0][i] = fabsf(den_r[i]); c_dn[1][i] = fabsf(den_g[i]); c_dn[2][i] = fabsf(den_b[i]); }

    f32x4 acc[2][2];
#pragma unroll
    for (int m = 0; m < 2; m++)
#pragma unroll
        for (int nn = 0; nn < 2; nn++) acc[m][nn] = (f32x4){0.f, 0.f, 0.f, 0.f};

    for (int k0 = 0; k0 < K2; k0 += 32) {
        bf16x8 av = *(const bf16x8*)&w2b[(co0 + trow) * K2 + k0 + tslot * 8];
        bf16x8 bv;
#pragma unroll
        for (int j = 0; j < 8; j++) {
            int k  = k0 + tslot * 8 + j;
            int ci = k / 9;
            int r9 = k - ci * 9;
            int kh = r9 / 3;
            int kw = r9 - kh * 3;
            bv[j] = act[abase + ci * (PH * PH) + kh * PH + kw];
        }
        *(bf16x8*)&lA[ldsW] = av;
        *(bf16x8*)&lB[ldsW] = bv;
        __syncthreads();

        const int ksl = lane >> 4;
        bf16x8 af[2], bfr[2];
#pragma unroll
        for (int m = 0; m < 2; m++) {
            int rr = wr * 32 + m * 16 + (lane & 15);
            af[m] = *(const bf16x8*)&lA[lidx(rr, ksl)];
        }
#pragma unroll
        for (int nn = 0; nn < 2; nn++) {
            int rc = wc * 32 + nn * 16 + (lane & 15);
            bfr[nn] = *(const bf16x8*)&lB[lidx(rc, ksl)];
        }
#pragma unroll
        for (int m = 0; m < 2; m++)
#pragma unroll
            for (int nn = 0; nn < 2; nn++)
                acc[m][nn] = __builtin_amdgcn_mfma_f32_16x16x32_bf16(af[m], bfr[nn], acc[m][nn], 0, 0, 0);
        __syncthreads();
    }

#pragma unroll
    for (int nn = 0; nn < 2; nn++) {
        const int pp  = p0 + wc * 32 + nn * 16 + (lane & 15);
        const int n2  = pp / 784;
        const int r2  = pp - n2 * 784;
        const int oh2 = r2 / 28;
        const int ow2 = r2 - oh2 * 28;
        const int obase = n2 * (COUT * 784) + oh2 * 28 + ow2;
#pragma unroll
        for (int m = 0; m < 2; m++) {
#pragma unroll
            for (int r = 0; r < 4; r++) {
                const int co = co0 + wr * 32 + m * 16 + ((lane >> 4) << 2) + r;
                const int var3 = co % 3;
                float nm[6], dn[4];
#pragma unroll
                for (int i = 0; i < 6; i++) nm[i] = (var3 == 0) ? c_nm[0][i] : ((var3 == 1) ? c_nm[1][i] : c_nm[2][i]);
#pragma unroll
                for (int i = 0; i < 4; i++) dn[i] = (var3 == 0) ? c_dn[0][i] : ((var3 == 1) ? c_dn[1][i] : c_dn[2][i]);
                const int oidx = obase + co * 784;
                float v = acc[m][nn][r] + bias2[co] + sc[oidx];
                out[oidx] = rational_eval(v, nm, dn);
            }
        }
    }
}

// ---------------- launcher ----------------
extern "C" void kernel_launch(void* const* d_in, const int* in_sizes, int n_in,
                              void* d_out, int out_size, void* d_ws, size_t ws_size,
                              hipStream_t stream)
{
    const float* x      = (const float*)d_in[0];
    const float* w1     = (const float*)d_in[1];
    const float* gamma1 = (const float*)d_in[2];
    const float* beta1  = (const float*)d_in[3];
    const float* mean1  = (const float*)d_in[4];
    const float* var1   = (const float*)d_in[5];
    const float* num_r  = (const float*)d_in[6];
    const float* den_r  = (const float*)d_in[7];
    const float* num_g  = (const float*)d_in[8];
    const float* den_g  = (const float*)d_in[9];
    const float* num_b  = (const float*)d_in[10];
    const float* den_b  = (const float*)d_in[11];
    const float* w2     = (const float*)d_in[12];
    const float* gamma2 = (const float*)d_in[13];
    const float* beta2  = (const float*)d_in[14];
    const float* mean2  = (const float*)d_in[15];
    const float* var2   = (const float*)d_in[16];
    const float* wsc    = (const float*)d_in[17];
    const float* gammas = (const float*)d_in[18];
    const float* betas  = (const float*)d_in[19];
    const float* means  = (const float*)d_in[20];
    const float* vars_  = (const float*)d_in[21];

    char* wsb_base = (char*)d_ws;
    short* w1b   = (short*)(wsb_base + W1B_OFF);
    short* w2b   = (short*)(wsb_base + W2B_OFF);
    short* wsb   = (short*)(wsb_base + WSB_OFF);
    float* s1    = (float*)(wsb_base + S1_OFF);
    float* s2    = (float*)(wsb_base + S2_OFF);
    float* ss    = (float*)(wsb_base + SS_OFF);
    float* bias1 = (float*)(wsb_base + B1_OFF);
    float* bias2 = (float*)(wsb_base + B2_OFF);
    float* biass = (float*)(wsb_base + BS_OFF);
    short* act   = (short*)(wsb_base + ACT_OFF);
    float* sc    = (float*)(wsb_base + SC_OFF);
    float* out   = (float*)d_out;

    // zero padded act (border ring must be 0 every call)
    hipMemsetAsync(wsb_base + ACT_OFF, 0, ACT_BYTES, stream);

    prep_scales_kernel<<<1, 192, 0, stream>>>(gamma1, beta1, mean1, var1,
                                              gamma2, beta2, mean2, var2,
                                              gammas, betas, means, vars_,
                                              s1, s2, ss, bias1, bias2, biass);

    prep_w_kernel<<<(COUT * K1 + 255) / 256, 256, 0, stream>>>(w1, s1, w1b, K1, COUT * K1);
    prep_w_kernel<<<(COUT * K2 + 255) / 256, 256, 0, stream>>>(w2, s2, w2b, K2, COUT * K2);
    prep_w_kernel<<<(COUT * KS + 255) / 256, 256, 0, stream>>>(wsc, ss, wsb, KS, COUT * KS);

    convA_kernel<<<3 * (NPIX / 64), 256, 0, stream>>>(x, w1b, wsb, bias1, biass,
                                                      num_r, den_r, num_g, den_g, num_b, den_b,
                                                      act, sc);

    convB_kernel<<<3 * (NPIX / 64), 256, 0, stream>>>(act, w2b, bias2, sc,
                                                      num_r, den_r, num_g, den_g, num_b, den_b,
                                                      out);
}

// Round 4
// 278.666 us; speedup vs baseline: 1.1815x; 1.1815x over previous
//
#include <hip/hip_runtime.h>

#define CIN    96
#define COUT   192
#define EPSBN  1e-5f
#define NPIX_BLOCKS 196   // 50176 pixels / 256 per block

// ---------------- ws layout (bytes) ----------------
// total = 61,702,144 B == round-1 footprint (proven to fit)
#define W1B_OFF  0u          // bf16 [192][9][96]   -> 331776 B
#define W2B_OFF  331776u     // bf16 [192][9][192]  -> 663552 B
#define WSB_OFF  995328u     // bf16 [192][96]      -> 36864 B
#define CS_OFF   1032192u    // 6 * 192 f32 -> 4608 B
#define XT_OFF   1048576u    // bf16 [64][56][56][96] -> 38535168 B (unpadded NHWC)
#define ACT_OFF  39583744u   // bf16 [64][30][30][192] -> 22118400 B (padded NHWC)

typedef __attribute__((ext_vector_type(8))) short bf16x8;
typedef __attribute__((ext_vector_type(4))) short bf16x4;
typedef __attribute__((ext_vector_type(4))) float f32x4;

__device__ __forceinline__ short f2bf(float f) {
    unsigned u = __float_as_uint(f);
    u += 0x7fffu + ((u >> 16) & 1u);
    return (short)(u >> 16);
}

// swizzled LDS index (shorts): [rows][32 k], 16B-slot XOR on (row>>1)&3 -> 2-way max (free)
__device__ __forceinline__ int lidx(int row, int slot) {
    return row * 32 + ((slot ^ ((row >> 1) & 3)) << 3);
}

__device__ __forceinline__ float rational_eval(float v, const float* nm, const float* dn) {
    float p = nm[5];
    p = p * v + nm[4];
    p = p * v + nm[3];
    p = p * v + nm[2];
    p = p * v + nm[1];
    p = p * v + nm[0];
    float xa = fabsf(v);
    float q = 1.0f;
    float pw = xa;
    q += dn[0] * pw; pw *= xa;
    q += dn[1] * pw; pw *= xa;
    q += dn[2] * pw; pw *= xa;
    q += dn[3] * pw;
    float inv = __builtin_amdgcn_rcpf(q);
    inv = inv * (2.0f - q * inv);   // one Newton step; q >= 1 so well-behaved
    return p * inv;
}

__device__ __forceinline__ void sel_coeffs(int v, const float cnm[3][6], const float cdn[3][4],
                                           float nm[6], float dn[4]) {
#pragma unroll
    for (int i = 0; i < 6; i++) nm[i] = (v == 0) ? cnm[0][i] : ((v == 1) ? cnm[1][i] : cnm[2][i]);
#pragma unroll
    for (int i = 0; i < 4; i++) dn[i] = (v == 0) ? cdn[0][i] : ((v == 1) ? cdn[1][i] : cdn[2][i]);
}

// ---------------- prep kernels ----------------
extern "C" __global__ void prep_scales_kernel(
    const float* g1, const float* b1, const float* m1, const float* v1,
    const float* g2, const float* b2, const float* m2, const float* v2,
    const float* gs, const float* bs, const float* ms, const float* vs,
    float* cs)
{
    int i = threadIdx.x;
    if (i < COUT) {
        float a1 = g1[i] * rsqrtf(v1[i] + EPSBN);
        float a2 = g2[i] * rsqrtf(v2[i] + EPSBN);
        float a3 = gs[i] * rsqrtf(vs[i] + EPSBN);
        cs[i]           = a1;
        cs[192 + i]     = a2;
        cs[384 + i]     = a3;
        cs[576 + i]     = b1[i] - m1[i] * a1;
        cs[768 + i]     = b2[i] - m2[i] * a2;
        cs[960 + i]     = bs[i] - ms[i] * a3;
    }
}

// w [co][ci][kpos] (OIHW flat, kpos=kh*3+kw, KP taps) -> wb [co][kpos][ci], scaled by s[co]
extern "C" __global__ void prep_w_kernel(const float* __restrict__ w, const float* __restrict__ s,
                                         short* __restrict__ wb, int CI, int KP, int total)
{
    int i = blockIdx.x * 256 + threadIdx.x;
    if (i >= total) return;
    int co = i / (CI * KP);
    int r  = i - co * CI * KP;
    int kpos = r / CI;
    int ci = r - kpos * CI;
    wb[i] = f2bf(w[(co * CI + ci) * KP + kpos] * s[co]);
}

// zero the border ring of a [64][H][H][C] bf16 buffer
extern "C" __global__ void ring_zero_kernel(short* __restrict__ buf, int H, int C, int total)
{
    int ring = 2 * H + 2 * (H - 2);
    int i = blockIdx.x * 256 + threadIdx.x;
    if (i >= total) return;
    int c = i % C;
    int t = i / C;
    int rp = t % ring;
    int n = t / ring;
    int h, w;
    if (rp < H)           { h = 0;          w = rp; }
    else if (rp < 2 * H)  { h = H - 1;      w = rp - H; }
    else { int k = rp - 2 * H; h = (k >> 1) + 1; w = (k & 1) ? (H - 1) : 0; }
    buf[((n * H + h) * H + w) * C + c] = 0;
}

// x NCHW f32 [64][96][56][56] -> xt NHWC bf16 [64][56][56][96] (unpadded)
extern "C" __global__ __launch_bounds__(256)
void xpose_kernel(const float* __restrict__ x, short* __restrict__ xt)
{
    __shared__ float t[96 * 57];
    int b = blockIdx.x;
    int n = b / 56, h = b - n * 56;
    const float* src = x + n * (96 * 3136) + h * 56;
    for (int i = threadIdx.x; i < 96 * 56; i += 256) {
        int c = i / 56, w = i - c * 56;
        t[c * 57 + w] = src[c * 3136 + w];
    }
    __syncthreads();
    short* dst = xt + (n * 56 + h) * 56 * 96;
    for (int i = threadIdx.x; i < 96 * 56; i += 256) {
        int w = i / 96, c = i - w * 96;
        dst[w * 96 + c] = f2bf(t[c * 57 + w]);
    }
}

// ---------------- kernel A: shortcut(1x1 s2)+BNs -> d_out (NCHW f32, as sc);
//                  conv1(3x3 s2)+BN1+rational -> act (NHWC bf16, padded) ----------------
extern "C" __global__ __launch_bounds__(256)
void convA_kernel(const short* __restrict__ xt,
                  const short* __restrict__ w1b,
                  const short* __restrict__ wsb,
                  const float* __restrict__ bias1,
                  const float* __restrict__ biass,
                  const float* __restrict__ num_r, const float* __restrict__ den_r,
                  const float* __restrict__ num_g, const float* __restrict__ den_g,
                  const float* __restrict__ num_b, const float* __restrict__ den_b,
                  short* __restrict__ act, float* __restrict__ outp)
{
    __shared__ short lA[64 * 32];
    __shared__ short lB[256 * 32];

    const int tid  = threadIdx.x;
    const int lane = tid & 63;
    const int wave = tid >> 6;
    const int co0  = (blockIdx.x % 3) * 64;
    const int p0   = (blockIdx.x / 3) * 256;

    // staging: A tile 64x32 -> 1 chunk/thread; B tile 256x32 -> 4 chunks/thread
    const int arow = tid >> 2;
    const int slot = tid & 3;
    const int awoff = lidx(arow, slot);
    int bwoff[4], xb0[4];
    bool top[4], left[4];
#pragma unroll
    for (int i = 0; i < 4; ++i) {
        int row = arow + i * 64;
        bwoff[i] = lidx(row, slot);
        int p = p0 + row;
        int n = p / 784; int pr = p - n * 784;
        int oh = pr / 28; int ow = pr - oh * 28;
        xb0[i] = ((n * 56 + 2 * oh) * 56 + 2 * ow) * 96 + slot * 8;  // unpadded (2oh,2ow)
        top[i]  = (oh == 0);
        left[i] = (ow == 0);
    }
    const int aw1 = (co0 + arow) * 864 + slot * 8;
    const int aws = (co0 + arow) * 96 + slot * 8;

    // MFMA-phase LDS read offsets
    const int ksl = lane >> 4;
    int ard[4], brd[4];
#pragma unroll
    for (int m = 0; m < 4; ++m) ard[m] = lidx(m * 16 + (lane & 15), ksl);
#pragma unroll
    for (int n = 0; n < 4; ++n) brd[n] = lidx(wave * 64 + n * 16 + (lane & 15), ksl);

    // ---------- shortcut GEMM (K=96, 3 steps), epilogue writes sc to outp ----------
    {
        f32x4 sacc[4][4];
#pragma unroll
        for (int m = 0; m < 4; m++)
#pragma unroll
            for (int n = 0; n < 4; n++) sacc[m][n] = (f32x4){0.f, 0.f, 0.f, 0.f};

#pragma unroll
        for (int cb = 0; cb < 3; ++cb) {
            bf16x8 av = *(const bf16x8*)&wsb[aws + cb * 32];
            bf16x8 bv[4];
#pragma unroll
            for (int i = 0; i < 4; ++i)
                bv[i] = *(const bf16x8*)&xt[xb0[i] + cb * 32];   // (2oh,2ow) always in-bounds
            *(bf16x8*)&lA[awoff] = av;
#pragma unroll
            for (int i = 0; i < 4; ++i) *(bf16x8*)&lB[bwoff[i]] = bv[i];
            __syncthreads();
            bf16x8 af[4], bfv[4];
#pragma unroll
            for (int m = 0; m < 4; ++m) af[m] = *(const bf16x8*)&lA[ard[m]];
#pragma unroll
            for (int n = 0; n < 4; ++n) bfv[n] = *(const bf16x8*)&lB[brd[n]];
#pragma unroll
            for (int m = 0; m < 4; ++m)
#pragma unroll
                for (int n = 0; n < 4; ++n)
                    sacc[m][n] = __builtin_amdgcn_mfma_f32_16x16x32_bf16(af[m], bfv[n], sacc[m][n], 0, 0, 0);
            __syncthreads();
        }

#pragma unroll
        for (int n = 0; n < 4; ++n) {
            int pp = p0 + wave * 64 + n * 16 + (lane & 15);
            int n2 = pp / 784; int r2 = pp - n2 * 784;
            int oh2 = r2 / 28; int ow2 = r2 - oh2 * 28;
            int obase = n2 * (COUT * 784) + oh2 * 28 + ow2;
#pragma unroll
            for (int m = 0; m < 4; ++m) {
                int cob = co0 + m * 16 + ((lane >> 4) << 2);
#pragma unroll
                for (int r = 0; r < 4; ++r)
                    outp[obase + (cob + r) * 784] = sacc[m][n][r] + biass[cob + r];
            }
        }
    }

    // ---------- conv1 GEMM (K=864: 9 kpos x 3 cb), zero-fill at top/left borders ----------
    f32x4 acc[4][4];
#pragma unroll
    for (int m = 0; m < 4; m++)
#pragma unroll
        for (int n = 0; n < 4; n++) acc[m][n] = (f32x4){0.f, 0.f, 0.f, 0.f};

    for (int kpos = 0; kpos < 9; ++kpos) {
        const int kh = kpos / 3;
        const int kw = kpos - kh * 3;
        const int bko = ((kh - 1) * 56 + (kw - 1)) * 96;  // offset from (2oh,2ow) to (2oh+kh-1,2ow+kw-1)
        const int ako = aw1 + kpos * 96;
        bool val[4];
#pragma unroll
        for (int i = 0; i < 4; ++i)
            val[i] = !((kh == 0) && top[i]) && !((kw == 0) && left[i]);
#pragma unroll
        for (int cb = 0; cb < 3; ++cb) {
            bf16x8 av = *(const bf16x8*)&w1b[ako + cb * 32];
            bf16x8 bv[4];
#pragma unroll
            for (int i = 0; i < 4; ++i) {
                bv[i] = (bf16x8)(short)0;
                if (val[i]) bv[i] = *(const bf16x8*)&xt[xb0[i] + bko + cb * 32];
            }
            *(bf16x8*)&lA[awoff] = av;
#pragma unroll
            for (int i = 0; i < 4; ++i) *(bf16x8*)&lB[bwoff[i]] = bv[i];
            __syncthreads();
            bf16x8 af[4], bfv[4];
#pragma unroll
            for (int m = 0; m < 4; ++m) af[m] = *(const bf16x8*)&lA[ard[m]];
#pragma unroll
            for (int n = 0; n < 4; ++n) bfv[n] = *(const bf16x8*)&lB[brd[n]];
#pragma unroll
            for (int m = 0; m < 4; ++m)
#pragma unroll
                for (int n = 0; n < 4; ++n)
                    acc[m][n] = __builtin_amdgcn_mfma_f32_16x16x32_bf16(af[m], bfv[n], acc[m][n], 0, 0, 0);
            __syncthreads();
        }
    }

    // ---------- conv1 epilogue: bias + rational -> act (NHWC, packed short4) ----------
    float cnm[3][6], cdn[3][4];
#pragma unroll
    for (int i = 0; i < 6; i++) { cnm[0][i] = num_r[i]; cnm[1][i] = num_g[i]; cnm[2][i] = num_b[i]; }
#pragma unroll
    for (int i = 0; i < 4; i++) { cdn[0][i] = fabsf(den_r[i]); cdn[1][i] = fabsf(den_g[i]); cdn[2][i] = fabsf(den_b[i]); }

    int abase[4];
#pragma unroll
    for (int n = 0; n < 4; ++n) {
        int pp = p0 + wave * 64 + n * 16 + (lane & 15);
        int n2 = pp / 784; int r2 = pp - n2 * 784;
        int oh2 = r2 / 28; int ow2 = r2 - oh2 * 28;
        abase[n] = ((n2 * 30 + oh2 + 1) * 30 + ow2 + 1) * 192;
    }
#pragma unroll
    for (int m = 0; m < 4; ++m) {
        int cob = co0 + m * 16 + ((lane >> 4) << 2);
        float res[4][4];
#pragma unroll
        for (int r = 0; r < 4; ++r) {
            float nm[6], dn[4];
            sel_coeffs((cob + r) % 3, cnm, cdn, nm, dn);
            float bv = bias1[cob + r];
#pragma unroll
            for (int n = 0; n < 4; ++n)
                res[n][r] = rational_eval(acc[m][n][r] + bv, nm, dn);
        }
#pragma unroll
        for (int n = 0; n < 4; ++n) {
            bf16x4 pk;
#pragma unroll
            for (int r = 0; r < 4; ++r) pk[r] = f2bf(res[n][r]);
            *(bf16x4*)&act[abase[n] + cob] = pk;
        }
    }
}

// ---------------- kernel B: conv2(3x3 s1)+BN2 + sc-add + rational -> out (NCHW f32) ----------------
extern "C" __global__ __launch_bounds__(256)
void convB_kernel(const short* __restrict__ act,
                  const short* __restrict__ w2b,
                  const float* __restrict__ bias2,
                  const float* __restrict__ num_r, const float* __restrict__ den_r,
                  const float* __restrict__ num_g, const float* __restrict__ den_g,
                  const float* __restrict__ num_b, const float* __restrict__ den_b,
                  float* __restrict__ outp)
{
    __shared__ short lA[64 * 32];
    __shared__ short lB[256 * 32];

    const int tid  = threadIdx.x;
    const int lane = tid & 63;
    const int wave = tid >> 6;
    const int co0  = (blockIdx.x % 3) * 64;
    const int p0   = (blockIdx.x / 3) * 256;

    const int arow = tid >> 2;
    const int slot = tid & 3;
    const int awoff = lidx(arow, slot);
    int bwoff[4], ab[4];
#pragma unroll
    for (int i = 0; i < 4; ++i) {
        int row = arow + i * 64;
        bwoff[i] = lidx(row, slot);
        int p = p0 + row;
        int n = p / 784; int pr = p - n * 784;
        int oh = pr / 28; int ow = pr - oh * 28;
        ab[i] = ((n * 30 + oh) * 30 + ow) * 192 + slot * 8;
    }
    const int aw2 = (co0 + arow) * 1728 + slot * 8;

    const int ksl = lane >> 4;
    int ard[4], brd[4];
#pragma unroll
    for (int m = 0; m < 4; ++m) ard[m] = lidx(m * 16 + (lane & 15), ksl);
#pragma unroll
    for (int n = 0; n < 4; ++n) brd[n] = lidx(wave * 64 + n * 16 + (lane & 15), ksl);

    f32x4 acc[4][4];
#pragma unroll
    for (int m = 0; m < 4; m++)
#pragma unroll
        for (int n = 0; n < 4; n++) acc[m][n] = (f32x4){0.f, 0.f, 0.f, 0.f};

    for (int kpos = 0; kpos < 9; ++kpos) {
        const int kh = kpos / 3;
        const int kw = kpos - kh * 3;
        const int bko = (kh * 30 + kw) * 192;
        const int ako = aw2 + kpos * 192;
#pragma unroll
        for (int cb = 0; cb < 6; ++cb) {
            bf16x8 av = *(const bf16x8*)&w2b[ako + cb * 32];
            bf16x8 bv[4];
#pragma unroll
            for (int i = 0; i < 4; ++i)
                bv[i] = *(const bf16x8*)&act[ab[i] + bko + cb * 32];
            *(bf16x8*)&lA[awoff] = av;
#pragma unroll
            for (int i = 0; i < 4; ++i) *(bf16x8*)&lB[bwoff[i]] = bv[i];
            __syncthreads();
            bf16x8 af[4], bfv[4];
#pragma unroll
            for (int m = 0; m < 4; ++m) af[m] = *(const bf16x8*)&lA[ard[m]];
#pragma unroll
            for (int n = 0; n < 4; ++n) bfv[n] = *(const bf16x8*)&lB[brd[n]];
#pragma unroll
            for (int m = 0; m < 4; ++m)
#pragma unroll
                for (int n = 0; n < 4; ++n)
                    acc[m][n] = __builtin_amdgcn_mfma_f32_16x16x32_bf16(af[m], bfv[n], acc[m][n], 0, 0, 0);
            __syncthreads();
        }
    }

    float cnm[3][6], cdn[3][4];
#pragma unroll
    for (int i = 0; i < 6; i++) { cnm[0][i] = num_r[i]; cnm[1][i] = num_g[i]; cnm[2][i] = num_b[i]; }
#pragma unroll
    for (int i = 0; i < 4; i++) { cdn[0][i] = fabsf(den_r[i]); cdn[1][i] = fabsf(den_g[i]); cdn[2][i] = fabsf(den_b[i]); }

    int obase[4];
#pragma unroll
    for (int n = 0; n < 4; ++n) {
        int pp = p0 + wave * 64 + n * 16 + (lane & 15);
        int n2 = pp / 784; int r2 = pp - n2 * 784;
        int oh2 = r2 / 28; int ow2 = r2 - oh2 * 28;
        obase[n] = n2 * (COUT * 784) + oh2 * 28 + ow2;
    }
#pragma unroll
    for (int m = 0; m < 4; ++m) {
        int cob = co0 + m * 16 + ((lane >> 4) << 2);
#pragma unroll
        for (int r = 0; r < 4; ++r) {
            float nm[6], dn[4];
            sel_coeffs((cob + r) % 3, cnm, cdn, nm, dn);
            float bv = bias2[cob + r];
#pragma unroll
            for (int n = 0; n < 4; ++n) {
                int idx = obase[n] + (cob + r) * 784;
                float v = acc[m][n][r] + bv + outp[idx];
                outp[idx] = rational_eval(v, nm, dn);
            }
        }
    }
}

// ---------------- launcher ----------------
extern "C" void kernel_launch(void* const* d_in, const int* in_sizes, int n_in,
                              void* d_out, int out_size, void* d_ws, size_t ws_size,
                              hipStream_t stream)
{
    const float* x      = (const float*)d_in[0];
    const float* w1     = (const float*)d_in[1];
    const float* gamma1 = (const float*)d_in[2];
    const float* beta1  = (const float*)d_in[3];
    const float* mean1  = (const float*)d_in[4];
    const float* var1   = (const float*)d_in[5];
    const float* num_r  = (const float*)d_in[6];
    const float* den_r  = (const float*)d_in[7];
    const float* num_g  = (const float*)d_in[8];
    const float* den_g  = (const float*)d_in[9];
    const float* num_b  = (const float*)d_in[10];
    const float* den_b  = (const float*)d_in[11];
    const float* w2     = (const float*)d_in[12];
    const float* gamma2 = (const float*)d_in[13];
    const float* beta2  = (const float*)d_in[14];
    const float* mean2  = (const float*)d_in[15];
    const float* var2   = (const float*)d_in[16];
    const float* wsc    = (const float*)d_in[17];
    const float* gammas = (const float*)d_in[18];
    const float* betas  = (const float*)d_in[19];
    const float* means  = (const float*)d_in[20];
    const float* vars_  = (const float*)d_in[21];

    char* base = (char*)d_ws;
    short* w1b  = (short*)(base + W1B_OFF);
    short* w2b  = (short*)(base + W2B_OFF);
    short* wsb  = (short*)(base + WSB_OFF);
    float* cs   = (float*)(base + CS_OFF);
    short* xt   = (short*)(base + XT_OFF);
    short* act  = (short*)(base + ACT_OFF);
    float* outp = (float*)d_out;

    float* bias1 = cs + 576;
    float* bias2 = cs + 768;
    float* biass = cs + 960;

    prep_scales_kernel<<<1, 192, 0, stream>>>(gamma1, beta1, mean1, var1,
                                              gamma2, beta2, mean2, var2,
                                              gammas, betas, means, vars_, cs);

    prep_w_kernel<<<(COUT * CIN * 9 + 255) / 256, 256, 0, stream>>>(w1, cs, w1b, CIN, 9, COUT * CIN * 9);
    prep_w_kernel<<<(COUT * COUT * 9 + 255) / 256, 256, 0, stream>>>(w2, cs + 192, w2b, COUT, 9, COUT * COUT * 9);
    prep_w_kernel<<<(COUT * CIN + 255) / 256, 256, 0, stream>>>(wsc, cs + 384, wsb, CIN, 1, COUT * CIN);

    // zero act pad ring (interior overwritten every call)
    {
        int tot_a = 64 * (2 * 30 + 2 * 28) * 192;
        ring_zero_kernel<<<(tot_a + 255) / 256, 256, 0, stream>>>(act, 30, 192, tot_a);
    }

    xpose_kernel<<<64 * 56, 256, 0, stream>>>(x, xt);

    convA_kernel<<<3 * NPIX_BLOCKS, 256, 0, stream>>>(xt, w1b, wsb, bias1, biass,
                                                      num_r, den_r, num_g, den_g, num_b, den_b,
                                                      act, outp);

    convB_kernel<<<3 * NPIX_BLOCKS, 256, 0, stream>>>(act, w2b, bias2,
                                                      num_r, den_r, num_g, den_g, num_b, den_b,
                                                      outp);
}

// Round 5
// 225.775 us; speedup vs baseline: 1.4582x; 1.2343x over previous
//
#include <hip/hip_runtime.h>

#define CIN    96
#define COUT   192
#define EPSBN  1e-5f
#define NPIX_BLOCKS 196   // 50176 pixels / 256 per block; grid = 3*196 = 588

// ---------------- ws layout (bytes), total 61,702,144 (proven fit) ----------------
#define W1B_OFF  0u          // bf16 [192][9][96]   -> 331776 B
#define W2B_OFF  331776u     // bf16 [192][9][192]  -> 663552 B
#define WSB_OFF  995328u     // bf16 [192][96]      -> 36864 B
#define CS_OFF   1032192u    // 6*192 f32 -> 4608 B
#define ZB_OFF   1040384u    // 128 B zero scratch (16B aligned)
#define XT_OFF   1048576u    // bf16 [64][56][56][96] -> 38535168 B (unpadded NHWC)
#define ACT_OFF  39583744u   // bf16 [64][30][30][192] -> 22118400 B (padded NHWC)

typedef __attribute__((ext_vector_type(8))) short bf16x8;
typedef __attribute__((ext_vector_type(4))) short bf16x4;
typedef __attribute__((ext_vector_type(4))) float f32x4;

__device__ __forceinline__ short f2bf(float f) {
    unsigned u = __float_as_uint(f);
    u += 0x7fffu + ((u >> 16) & 1u);
    return (short)(u >> 16);
}

// swizzled LDS read index (shorts): [rows][32 k], 16B-slot XOR on (row>>1)&3
__device__ __forceinline__ int lidx(int row, int slot) {
    return row * 32 + ((slot ^ ((row >> 1) & 3)) << 3);
}

// direct global->LDS, 16B per lane; LDS dest = uniform base + lane*16
__device__ __forceinline__ void gload16(const short* g, short* l) {
    __builtin_amdgcn_global_load_lds(
        (const __attribute__((address_space(1))) void*)g,
        (__attribute__((address_space(3))) void*)l, 16, 0, 0);
}

// bijective XCD chunk swizzle for nwg=588 (q=73, r=4): same-pixel-tile blocks -> same XCD
__device__ __forceinline__ int swz_bid(int bid) {
    int xcd = bid & 7, lin = bid >> 3;
    int base = (xcd < 4) ? xcd * 74 : 296 + (xcd - 4) * 73;
    return base + lin;
}

__device__ __forceinline__ float rational_eval(float v, const float* nm, const float* dn) {
    float p = nm[5];
    p = p * v + nm[4];
    p = p * v + nm[3];
    p = p * v + nm[2];
    p = p * v + nm[1];
    p = p * v + nm[0];
    float xa = fabsf(v);
    float q = 1.0f;
    float pw = xa;
    q += dn[0] * pw; pw *= xa;
    q += dn[1] * pw; pw *= xa;
    q += dn[2] * pw; pw *= xa;
    q += dn[3] * pw;
    float inv = __builtin_amdgcn_rcpf(q);
    inv = inv * (2.0f - q * inv);
    return p * inv;
}

__device__ __forceinline__ void sel_coeffs(int v, const float cnm[3][6], const float cdn[3][4],
                                           float nm[6], float dn[4]) {
#pragma unroll
    for (int i = 0; i < 6; i++) nm[i] = (v == 0) ? cnm[0][i] : ((v == 1) ? cnm[1][i] : cnm[2][i]);
#pragma unroll
    for (int i = 0; i < 4; i++) dn[i] = (v == 0) ? cdn[0][i] : ((v == 1) ? cdn[1][i] : cdn[2][i]);
}

#define COMPUTE(A, buf)                                                                        \
    do {                                                                                       \
        bf16x8 af[4], bfv[4];                                                                  \
        _Pragma("unroll") for (int m_ = 0; m_ < 4; ++m_) af[m_] =                              \
            *(const bf16x8*)&lA[buf][ard[m_]];                                                 \
        _Pragma("unroll") for (int n_ = 0; n_ < 4; ++n_) bfv[n_] =                             \
            *(const bf16x8*)&lB[buf][brd[n_]];                                                 \
        _Pragma("unroll") for (int m_ = 0; m_ < 4; ++m_)                                       \
            _Pragma("unroll") for (int n_ = 0; n_ < 4; ++n_)                                   \
                A[m_][n_] = __builtin_amdgcn_mfma_f32_16x16x32_bf16(af[m_], bfv[n_],           \
                                                                    A[m_][n_], 0, 0, 0);      \
    } while (0)

// ---------------- prep kernels ----------------
extern "C" __global__ void prep_scales_kernel(
    const float* g1, const float* b1, const float* m1, const float* v1,
    const float* g2, const float* b2, const float* m2, const float* v2,
    const float* gs, const float* bs, const float* ms, const float* vs,
    float* cs, float* zb)
{
    int i = threadIdx.x;
    if (i < 32) zb[i] = 0.f;
    if (i < COUT) {
        float a1 = g1[i] * rsqrtf(v1[i] + EPSBN);
        float a2 = g2[i] * rsqrtf(v2[i] + EPSBN);
        float a3 = gs[i] * rsqrtf(vs[i] + EPSBN);
        cs[i]       = a1;
        cs[192 + i] = a2;
        cs[384 + i] = a3;
        cs[576 + i] = b1[i] - m1[i] * a1;
        cs[768 + i] = b2[i] - m2[i] * a2;
        cs[960 + i] = bs[i] - ms[i] * a3;
    }
}

// w [co][ci][kpos] (OIHW) -> wb [co][kpos][ci], scaled by s[co]
extern "C" __global__ void prep_w_kernel(const float* __restrict__ w, const float* __restrict__ s,
                                         short* __restrict__ wb, int CI, int KP, int total)
{
    int i = blockIdx.x * 256 + threadIdx.x;
    if (i >= total) return;
    int co = i / (CI * KP);
    int r  = i - co * CI * KP;
    int kpos = r / CI;
    int ci = r - kpos * CI;
    wb[i] = f2bf(w[(co * CI + ci) * KP + kpos] * s[co]);
}

// zero the border ring of a [64][H][H][C] bf16 buffer
extern "C" __global__ void ring_zero_kernel(short* __restrict__ buf, int H, int C, int total)
{
    int ring = 2 * H + 2 * (H - 2);
    int i = blockIdx.x * 256 + threadIdx.x;
    if (i >= total) return;
    int c = i % C;
    int t = i / C;
    int rp = t % ring;
    int n = t / ring;
    int h, w;
    if (rp < H)           { h = 0;          w = rp; }
    else if (rp < 2 * H)  { h = H - 1;      w = rp - H; }
    else { int k = rp - 2 * H; h = (k >> 1) + 1; w = (k & 1) ? (H - 1) : 0; }
    buf[((n * H + h) * H + w) * C + c] = 0;
}

// x NCHW f32 [64][96][56][56] -> xt NHWC bf16 [64][56][56][96]
extern "C" __global__ __launch_bounds__(256)
void xpose_kernel(const float* __restrict__ x, short* __restrict__ xt)
{
    __shared__ float t[96 * 57];
    int b = blockIdx.x;
    int n = b / 56, h = b - n * 56;
    const float* src = x + n * (96 * 3136) + h * 56;
    for (int i = threadIdx.x; i < 96 * 56; i += 256) {
        int c = i / 56, w = i - c * 56;
        t[c * 57 + w] = src[c * 3136 + w];
    }
    __syncthreads();
    short* dst = xt + (n * 56 + h) * 56 * 96;
    for (int i = threadIdx.x; i < 96 * 56; i += 256) {
        int w = i / 96, c = i - w * 96;
        dst[w * 96 + c] = f2bf(t[c * 57 + w]);
    }
}

// ---------------- kernel A: shortcut(1x1 s2)+BNs -> d_out (NCHW f32, as sc);
//                  conv1(3x3 s2)+BN1+rational -> act (NHWC bf16, padded) ----------------
extern "C" __global__ __launch_bounds__(256)
void convA_kernel(const short* __restrict__ xt,
                  const short* __restrict__ w1b,
                  const short* __restrict__ wsb,
                  const short* __restrict__ zbuf,
                  const float* __restrict__ bias1,
                  const float* __restrict__ biass,
                  const float* __restrict__ num_r, const float* __restrict__ den_r,
                  const float* __restrict__ num_g, const float* __restrict__ den_g,
                  const float* __restrict__ num_b, const float* __restrict__ den_b,
                  short* __restrict__ act, float* __restrict__ outp)
{
    __shared__ short lA[2][2048];
    __shared__ short lB[2][8192];

    const int tid  = threadIdx.x;
    const int lane = tid & 63;
    const int wave = tid >> 6;
    const int lbid = swz_bid(blockIdx.x);
    const int co0  = (lbid % 3) * 64;
    const int p0   = (lbid / 3) * 256;

    // staging geometry: thread -> (row = tid>>2, linear 16B slot = tid&3)
    // swizzled content: load global slot s' = s ^ ((row>>1)&3) = (tid&3)^((tid>>3)&3)
    const int swz8 = (((tid & 3) ^ ((tid >> 3) & 3))) * 8;
    const int arow = tid >> 2;
    int xb0[4];
    bool top[4], left[4];
#pragma unroll
    for (int i = 0; i < 4; ++i) {
        int row = arow + i * 64;
        int p = p0 + row;
        int n = p / 784; int pr = p - n * 784;
        int oh = pr / 28; int ow = pr - oh * 28;
        xb0[i] = ((n * 56 + 2 * oh) * 56 + 2 * ow) * 96 + swz8;  // (2oh,2ow), unpadded
        top[i]  = (oh == 0);
        left[i] = (ow == 0);
    }
    const int aw1 = (co0 + arow) * 864 + swz8;
    const int aws = (co0 + arow) * 96 + swz8;

    // MFMA-phase LDS read offsets (swizzled)
    const int ksl = lane >> 4;
    int ard[4], brd[4];
#pragma unroll
    for (int m = 0; m < 4; ++m) ard[m] = lidx(m * 16 + (lane & 15), ksl);
#pragma unroll
    for (int n = 0; n < 4; ++n) brd[n] = lidx(wave * 64 + n * 16 + (lane & 15), ksl);

    auto stageS = [&](int buf, int cb) {
        gload16(&wsb[aws + cb * 32], &lA[buf][wave * 512]);
#pragma unroll
        for (int i = 0; i < 4; ++i)
            gload16(&xt[xb0[i] + cb * 32], &lB[buf][i * 2048 + wave * 512]);
    };
    auto stage1 = [&](int buf, int t) {
        int kpos = t / 3, cb = t - 3 * kpos;
        int kh = kpos / 3, kw = kpos - kh * 3;
        int bko = ((kh - 1) * 56 + (kw - 1)) * 96 + cb * 32;
        int ako = kpos * 96 + cb * 32;
        gload16(&w1b[aw1 + ako], &lA[buf][wave * 512]);
#pragma unroll
        for (int i = 0; i < 4; ++i) {
            const short* src = (((kh == 0) && top[i]) || ((kw == 0) && left[i]))
                             ? zbuf : &xt[xb0[i] + bko];
            gload16(src, &lB[buf][i * 2048 + wave * 512]);
        }
    };

    // ---------- shortcut GEMM (K=96, 3 pipelined steps) ----------
    f32x4 sacc[4][4];
#pragma unroll
    for (int m = 0; m < 4; m++)
#pragma unroll
        for (int n = 0; n < 4; n++) sacc[m][n] = (f32x4){0.f, 0.f, 0.f, 0.f};

    stageS(0, 0);
    int cur = 0;
#pragma unroll
    for (int cb = 0; cb < 3; ++cb) {
        __syncthreads();
        if (cb < 2) stageS(cur ^ 1, cb + 1);
        else        stage1(cur ^ 1, 0);       // chain into conv1 pipeline
        COMPUTE(sacc, cur);
        cur ^= 1;
    }

    // sc epilogue (overlaps conv1's first staged loads)
#pragma unroll
    for (int n = 0; n < 4; ++n) {
        int pp = p0 + wave * 64 + n * 16 + (lane & 15);
        int n2 = pp / 784; int r2 = pp - n2 * 784;
        int oh2 = r2 / 28; int ow2 = r2 - oh2 * 28;
        int obase = n2 * (COUT * 784) + oh2 * 28 + ow2;
#pragma unroll
        for (int m = 0; m < 4; ++m) {
            int cob = co0 + m * 16 + ((lane >> 4) << 2);
#pragma unroll
            for (int r = 0; r < 4; ++r)
                outp[obase + (cob + r) * 784] = sacc[m][n][r] + biass[cob + r];
        }
    }

    // ---------- conv1 GEMM (K=864: 27 pipelined steps) ----------
    f32x4 acc[4][4];
#pragma unroll
    for (int m = 0; m < 4; m++)
#pragma unroll
        for (int n = 0; n < 4; n++) acc[m][n] = (f32x4){0.f, 0.f, 0.f, 0.f};

    for (int t = 0; t < 27; ++t) {
        __syncthreads();
        if (t < 26) stage1(cur ^ 1, t + 1);
        COMPUTE(acc, cur);
        cur ^= 1;
    }

    // conv1 epilogue: bias + rational -> act (NHWC, packed short4)
    float cnm[3][6], cdn[3][4];
#pragma unroll
    for (int i = 0; i < 6; i++) { cnm[0][i] = num_r[i]; cnm[1][i] = num_g[i]; cnm[2][i] = num_b[i]; }
#pragma unroll
    for (int i = 0; i < 4; i++) { cdn[0][i] = fabsf(den_r[i]); cdn[1][i] = fabsf(den_g[i]); cdn[2][i] = fabsf(den_b[i]); }

    int abase[4];
#pragma unroll
    for (int n = 0; n < 4; ++n) {
        int pp = p0 + wave * 64 + n * 16 + (lane & 15);
        int n2 = pp / 784; int r2 = pp - n2 * 784;
        int oh2 = r2 / 28; int ow2 = r2 - oh2 * 28;
        abase[n] = ((n2 * 30 + oh2 + 1) * 30 + ow2 + 1) * 192;
    }
#pragma unroll
    for (int m = 0; m < 4; ++m) {
        int cob = co0 + m * 16 + ((lane >> 4) << 2);
        float res[4][4];
#pragma unroll
        for (int r = 0; r < 4; ++r) {
            float nm[6], dn[4];
            sel_coeffs((cob + r) % 3, cnm, cdn, nm, dn);
            float bv = bias1[cob + r];
#pragma unroll
            for (int n = 0; n < 4; ++n)
                res[n][r] = rational_eval(acc[m][n][r] + bv, nm, dn);
        }
#pragma unroll
        for (int n = 0; n < 4; ++n) {
            bf16x4 pk;
#pragma unroll
            for (int r = 0; r < 4; ++r) pk[r] = f2bf(res[n][r]);
            *(bf16x4*)&act[abase[n] + cob] = pk;
        }
    }
}

// ---------------- kernel B: conv2(3x3 s1)+BN2 + sc-add + rational -> out (NCHW f32) ----------------
extern "C" __global__ __launch_bounds__(256)
void convB_kernel(const short* __restrict__ act,
                  const short* __restrict__ w2b,
                  const float* __restrict__ bias2,
                  const float* __restrict__ num_r, const float* __restrict__ den_r,
                  const float* __restrict__ num_g, const float* __restrict__ den_g,
                  const float* __restrict__ num_b, const float* __restrict__ den_b,
                  float* __restrict__ outp)
{
    __shared__ short lA[2][2048];
    __shared__ short lB[2][8192];

    const int tid  = threadIdx.x;
    const int lane = tid & 63;
    const int wave = tid >> 6;
    const int lbid = swz_bid(blockIdx.x);
    const int co0  = (lbid % 3) * 64;
    const int p0   = (lbid / 3) * 256;

    const int swz8 = (((tid & 3) ^ ((tid >> 3) & 3))) * 8;
    const int arow = tid >> 2;
    int ab[4];
#pragma unroll
    for (int i = 0; i < 4; ++i) {
        int row = arow + i * 64;
        int p = p0 + row;
        int n = p / 784; int pr = p - n * 784;
        int oh = pr / 28; int ow = pr - oh * 28;
        ab[i] = ((n * 30 + oh) * 30 + ow) * 192 + swz8;   // padded act, (kh,kw) adds (kh*30+kw)*192
    }
    const int awg = (co0 + arow) * 1728 + swz8;

    const int ksl = lane >> 4;
    int ard[4], brd[4];
#pragma unroll
    for (int m = 0; m < 4; ++m) ard[m] = lidx(m * 16 + (lane & 15), ksl);
#pragma unroll
    for (int n = 0; n < 4; ++n) brd[n] = lidx(wave * 64 + n * 16 + (lane & 15), ksl);

    auto stage = [&](int buf, int t) {
        int kpos = t / 6, cb = t - 6 * kpos;
        int kh = kpos / 3, kw = kpos - kh * 3;
        int bko = (kh * 30 + kw) * 192 + cb * 32;
        int ako = kpos * 192 + cb * 32;
        gload16(&w2b[awg + ako], &lA[buf][wave * 512]);
#pragma unroll
        for (int i = 0; i < 4; ++i)
            gload16(&act[ab[i] + bko], &lB[buf][i * 2048 + wave * 512]);
    };

    f32x4 acc[4][4];
#pragma unroll
    for (int m = 0; m < 4; m++)
#pragma unroll
        for (int n = 0; n < 4; n++) acc[m][n] = (f32x4){0.f, 0.f, 0.f, 0.f};

    stage(0, 0);
    int cur = 0;
    for (int t = 0; t < 54; ++t) {
        __syncthreads();            // drains own vmcnt before barrier -> buf[cur] ready
        if (t < 53) stage(cur ^ 1, t + 1);
        COMPUTE(acc, cur);
        cur ^= 1;
    }

    float cnm[3][6], cdn[3][4];
#pragma unroll
    for (int i = 0; i < 6; i++) { cnm[0][i] = num_r[i]; cnm[1][i] = num_g[i]; cnm[2][i] = num_b[i]; }
#pragma unroll
    for (int i = 0; i < 4; i++) { cdn[0][i] = fabsf(den_r[i]); cdn[1][i] = fabsf(den_g[i]); cdn[2][i] = fabsf(den_b[i]); }

    int obase[4];
#pragma unroll
    for (int n = 0; n < 4; ++n) {
        int pp = p0 + wave * 64 + n * 16 + (lane & 15);
        int n2 = pp / 784; int r2 = pp - n2 * 784;
        int oh2 = r2 / 28; int ow2 = r2 - oh2 * 28;
        obase[n] = n2 * (COUT * 784) + oh2 * 28 + ow2;
    }
#pragma unroll
    for (int m = 0; m < 4; ++m) {
        int cob = co0 + m * 16 + ((lane >> 4) << 2);
#pragma unroll
        for (int r = 0; r < 4; ++r) {
            float nm[6], dn[4];
            sel_coeffs((cob + r) % 3, cnm, cdn, nm, dn);
            float bv = bias2[cob + r];
#pragma unroll
            for (int n = 0; n < 4; ++n) {
                int idx = obase[n] + (cob + r) * 784;
                float v = acc[m][n][r] + bv + outp[idx];
                outp[idx] = rational_eval(v, nm, dn);
            }
        }
    }
}

// ---------------- launcher ----------------
extern "C" void kernel_launch(void* const* d_in, const int* in_sizes, int n_in,
                              void* d_out, int out_size, void* d_ws, size_t ws_size,
                              hipStream_t stream)
{
    const float* x      = (const float*)d_in[0];
    const float* w1     = (const float*)d_in[1];
    const float* gamma1 = (const float*)d_in[2];
    const float* beta1  = (const float*)d_in[3];
    const float* mean1  = (const float*)d_in[4];
    const float* var1   = (const float*)d_in[5];
    const float* num_r  = (const float*)d_in[6];
    const float* den_r  = (const float*)d_in[7];
    const float* num_g  = (const float*)d_in[8];
    const float* den_g  = (const float*)d_in[9];
    const float* num_b  = (const float*)d_in[10];
    const float* den_b  = (const float*)d_in[11];
    const float* w2     = (const float*)d_in[12];
    const float* gamma2 = (const float*)d_in[13];
    const float* beta2  = (const float*)d_in[14];
    const float* mean2  = (const float*)d_in[15];
    const float* var2   = (const float*)d_in[16];
    const float* wsc    = (const float*)d_in[17];
    const float* gammas = (const float*)d_in[18];
    const float* betas  = (const float*)d_in[19];
    const float* means  = (const float*)d_in[20];
    const float* vars_  = (const float*)d_in[21];

    char* base = (char*)d_ws;
    short* w1b  = (short*)(base + W1B_OFF);
    short* w2b  = (short*)(base + W2B_OFF);
    short* wsb  = (short*)(base + WSB_OFF);
    float* cs   = (float*)(base + CS_OFF);
    float* zb   = (float*)(base + ZB_OFF);
    short* xt   = (short*)(base + XT_OFF);
    short* act  = (short*)(base + ACT_OFF);
    float* outp = (float*)d_out;

    float* bias1 = cs + 576;
    float* bias2 = cs + 768;
    float* biass = cs + 960;

    prep_scales_kernel<<<1, 256, 0, stream>>>(gamma1, beta1, mean1, var1,
                                              gamma2, beta2, mean2, var2,
                                              gammas, betas, means, vars_, cs, zb);

    prep_w_kernel<<<(COUT * CIN * 9 + 255) / 256, 256, 0, stream>>>(w1, cs, w1b, CIN, 9, COUT * CIN * 9);
    prep_w_kernel<<<(COUT * COUT * 9 + 255) / 256, 256, 0, stream>>>(w2, cs + 192, w2b, COUT, 9, COUT * COUT * 9);
    prep_w_kernel<<<(COUT * CIN + 255) / 256, 256, 0, stream>>>(wsc, cs + 384, wsb, CIN, 1, COUT * CIN);

    {
        int tot_a = 64 * (2 * 30 + 2 * 28) * 192;
        ring_zero_kernel<<<(tot_a + 255) / 256, 256, 0, stream>>>(act, 30, 192, tot_a);
    }

    xpose_kernel<<<64 * 56, 256, 0, stream>>>(x, xt);

    convA_kernel<<<3 * NPIX_BLOCKS, 256, 0, stream>>>(xt, w1b, wsb, (const short*)zb, bias1, biass,
                                                      num_r, den_r, num_g, den_g, num_b, den_b,
                                                      act, outp);

    convB_kernel<<<3 * NPIX_BLOCKS, 256, 0, stream>>>(act, w2b, bias2,
                                                      num_r, den_r, num_g, den_g, num_b, den_b,
                                                      outp);
}

// Round 6
// 210.429 us; speedup vs baseline: 1.5646x; 1.0729x over previous
//
#include <hip/hip_runtime.h>

#define CIN    96
#define COUT   192
#define EPSBN  1e-5f
#define NPB    392           // 50176 pixels / 128 per block
#define GRID   (3 * NPB)     // 1176 = 8 * 147

// ---------------- ws layout (bytes), total < 61,702,144 (proven fit) ----------------
#define W1B_OFF  0u          // bf16 [192][9][96]   -> 331776 B
#define W2B_OFF  331776u     // bf16 [192][9][192]  -> 663552 B
#define WSB_OFF  995328u     // bf16 [192][96]      -> 36864 B
#define CS_OFF   1032192u    // 6*192 f32 -> 4608 B
#define ZB_OFF   1040384u    // 128 B zero scratch
#define XT_OFF   1048576u    // bf16 [64][56][56][96] -> 38535168 B (unpadded NHWC)
#define ACT_OFF  39583744u   // bf16 [64][30][30][192] -> 22118400 B (padded NHWC)

typedef __attribute__((ext_vector_type(8))) short bf16x8;
typedef __attribute__((ext_vector_type(4))) short bf16x4;
typedef __attribute__((ext_vector_type(4))) float f32x4;

__device__ __forceinline__ short f2bf(float f) {
    unsigned u = __float_as_uint(f);
    u += 0x7fffu + ((u >> 16) & 1u);
    return (short)(u >> 16);
}

// swizzled LDS read index (shorts): [rows][32 k], 16B-slot XOR on (row>>1)&3
__device__ __forceinline__ int lidx(int row, int slot) {
    return row * 32 + ((slot ^ ((row >> 1) & 3)) << 3);
}

// direct global->LDS, 16B per lane; LDS dest = wave-uniform base + lane*16
__device__ __forceinline__ void gload16(const short* g, short* l) {
    __builtin_amdgcn_global_load_lds(
        (const __attribute__((address_space(1))) void*)g,
        (__attribute__((address_space(3))) void*)l, 16, 0, 0);
}

// bijective XCD chunk swizzle: grid 1176 = 8 * 147; 147 % 3 == 0 keeps
// the 3 co-blocks of one pixel tile on one XCD.
__device__ __forceinline__ int swz_bid(int bid) {
    return (bid & 7) * 147 + (bid >> 3);
}

__device__ __forceinline__ int nxt3(int b) { return b == 2 ? 0 : b + 1; }

__device__ __forceinline__ float rational_eval(float v, const float* nm, const float* dn) {
    float p = nm[5];
    p = p * v + nm[4];
    p = p * v + nm[3];
    p = p * v + nm[2];
    p = p * v + nm[1];
    p = p * v + nm[0];
    float xa = fabsf(v);
    float q = 1.0f;
    float pw = xa;
    q += dn[0] * pw; pw *= xa;
    q += dn[1] * pw; pw *= xa;
    q += dn[2] * pw; pw *= xa;
    q += dn[3] * pw;
    float inv = __builtin_amdgcn_rcpf(q);
    inv = inv * (2.0f - q * inv);
    return p * inv;
}

__device__ __forceinline__ void sel_coeffs(int v, const float cnm[3][6], const float cdn[3][4],
                                           float nm[6], float dn[4]) {
#pragma unroll
    for (int i = 0; i < 6; i++) nm[i] = (v == 0) ? cnm[0][i] : ((v == 1) ? cnm[1][i] : cnm[2][i]);
#pragma unroll
    for (int i = 0; i < 4; i++) dn[i] = (v == 0) ? cdn[0][i] : ((v == 1) ? cdn[1][i] : cdn[2][i]);
}

// 4x2 fragment compute on buffer `buf`
#define COMPUTE(A, buf)                                                                        \
    do {                                                                                       \
        bf16x8 af[4], bfv[2];                                                                  \
        _Pragma("unroll") for (int m_ = 0; m_ < 4; ++m_) af[m_] =                              \
            *(const bf16x8*)&lA[(buf) * 2048 + ard[m_]];                                       \
        _Pragma("unroll") for (int n_ = 0; n_ < 2; ++n_) bfv[n_] =                             \
            *(const bf16x8*)&lB[(buf) * 4096 + brd[n_]];                                       \
        _Pragma("unroll") for (int m_ = 0; m_ < 4; ++m_)                                       \
            _Pragma("unroll") for (int n_ = 0; n_ < 2; ++n_)                                   \
                A[m_][n_] = __builtin_amdgcn_mfma_f32_16x16x32_bf16(af[m_], bfv[n_],           \
                                                                    A[m_][n_], 0, 0, 0);      \
    } while (0)

#define WAITV(N) asm volatile("s_waitcnt vmcnt(" #N ")" ::: "memory")

// ---------------- prep kernels ----------------
extern "C" __global__ void prep_scales_kernel(
    const float* g1, const float* b1, const float* m1, const float* v1,
    const float* g2, const float* b2, const float* m2, const float* v2,
    const float* gs, const float* bs, const float* ms, const float* vs,
    float* cs, float* zb)
{
    int i = threadIdx.x;
    if (i < 32) zb[i] = 0.f;
    if (i < COUT) {
        float a1 = g1[i] * rsqrtf(v1[i] + EPSBN);
        float a2 = g2[i] * rsqrtf(v2[i] + EPSBN);
        float a3 = gs[i] * rsqrtf(vs[i] + EPSBN);
        cs[i]       = a1;
        cs[192 + i] = a2;
        cs[384 + i] = a3;
        cs[576 + i] = b1[i] - m1[i] * a1;                       // bias1
        cs[768 + i] = (b2[i] - m2[i] * a2) + (bs[i] - ms[i] * a3);  // bias2 + biass (fused)
    }
}

// w [co][ci][kpos] (OIHW) -> wb [co][kpos][ci], scaled by s[co]
extern "C" __global__ void prep_w_kernel(const float* __restrict__ w, const float* __restrict__ s,
                                         short* __restrict__ wb, int CI, int KP, int total)
{
    int i = blockIdx.x * 256 + threadIdx.x;
    if (i >= total) return;
    int co = i / (CI * KP);
    int r  = i - co * CI * KP;
    int kpos = r / CI;
    int ci = r - kpos * CI;
    wb[i] = f2bf(w[(co * CI + ci) * KP + kpos] * s[co]);
}

// zero the border ring of a [64][H][H][C] bf16 buffer
extern "C" __global__ void ring_zero_kernel(short* __restrict__ buf, int H, int C, int total)
{
    int ring = 2 * H + 2 * (H - 2);
    int i = blockIdx.x * 256 + threadIdx.x;
    if (i >= total) return;
    int c = i % C;
    int t = i / C;
    int rp = t % ring;
    int n = t / ring;
    int h, w;
    if (rp < H)           { h = 0;          w = rp; }
    else if (rp < 2 * H)  { h = H - 1;      w = rp - H; }
    else { int k = rp - 2 * H; h = (k >> 1) + 1; w = (k & 1) ? (H - 1) : 0; }
    buf[((n * H + h) * H + w) * C + c] = 0;
}

// x NCHW f32 [64][96][56][56] -> xt NHWC bf16 [64][56][56][96]
extern "C" __global__ __launch_bounds__(256)
void xpose_kernel(const float* __restrict__ x, short* __restrict__ xt)
{
    __shared__ float t[96 * 57];
    int b = blockIdx.x;
    int n = b / 56, h = b - n * 56;
    const float* src = x + n * (96 * 3136) + h * 56;
    for (int i = threadIdx.x; i < 96 * 56; i += 256) {
        int c = i / 56, w = i - c * 56;
        t[c * 57 + w] = src[c * 3136 + w];
    }
    __syncthreads();
    short* dst = xt + (n * 56 + h) * 56 * 96;
    for (int i = threadIdx.x; i < 96 * 56; i += 256) {
        int w = i / 96, c = i - w * 96;
        dst[w * 96 + c] = f2bf(t[c * 57 + w]);
    }
}

// ---------------- kernel A: conv1(3x3 s2)+BN1+rational -> act (NHWC bf16, padded) ----------------
extern "C" __global__ __launch_bounds__(256)
void convA_kernel(const short* __restrict__ xt,
                  const short* __restrict__ w1b,
                  const short* __restrict__ zbuf,
                  const float* __restrict__ bias1,
                  const float* __restrict__ num_r, const float* __restrict__ den_r,
                  const float* __restrict__ num_g, const float* __restrict__ den_g,
                  const float* __restrict__ num_b, const float* __restrict__ den_b,
                  short* __restrict__ act)
{
    __shared__ short lA[3 * 2048];   // 64 x 32 per buffer
    __shared__ short lB[3 * 4096];   // 128 x 32 per buffer

    const int tid  = threadIdx.x;
    const int lane = tid & 63;
    const int wave = tid >> 6;
    const int lbid = swz_bid(blockIdx.x);
    const int co0  = (lbid % 3) * 64;
    const int p0   = (lbid / 3) * 128;

    // staging geometry: thread -> (row = tid>>2, linear 16B slot = tid&3);
    // source uses swizzled slot so linear LDS + lidx() reads line up.
    const int swz8 = ((tid & 3) ^ ((tid >> 3) & 3)) * 8;
    const int arow = tid >> 2;
    int xb0[2];
    bool top[2], left[2];
#pragma unroll
    for (int i = 0; i < 2; ++i) {
        int p = p0 + arow + i * 64;
        int n = p / 784; int pr = p - n * 784;
        int oh = pr / 28; int ow = pr - oh * 28;
        xb0[i] = ((n * 56 + 2 * oh) * 56 + 2 * ow) * 96 + swz8;
        top[i]  = (oh == 0);
        left[i] = (ow == 0);
    }
    const int aw1 = (co0 + arow) * 864 + swz8;

    const int ksl = lane >> 4;
    int ard[4], brd[2];
#pragma unroll
    for (int m = 0; m < 4; ++m) ard[m] = lidx(m * 16 + (lane & 15), ksl);
#pragma unroll
    for (int n = 0; n < 2; ++n) brd[n] = lidx(wave * 32 + n * 16 + (lane & 15), ksl);

    auto stage = [&](int buf, int t) {
        int kpos = t / 3, cb = t - 3 * kpos;       // uniform SALU
        int kh = kpos / 3, kw = kpos - 3 * kh;
        int bko = ((kh - 1) * 56 + (kw - 1)) * 96 + cb * 32;
        gload16(&w1b[aw1 + kpos * 96 + cb * 32], &lA[buf * 2048 + wave * 512]);
#pragma unroll
        for (int i = 0; i < 2; ++i) {
            const short* src = (((kh == 0) && top[i]) || ((kw == 0) && left[i]))
                             ? zbuf : &xt[xb0[i] + bko];
            gload16(src, &lB[buf * 4096 + i * 2048 + wave * 512]);
        }
    };

    f32x4 acc[4][2];
#pragma unroll
    for (int m = 0; m < 4; m++)
#pragma unroll
        for (int n = 0; n < 2; n++) acc[m][n] = (f32x4){0.f, 0.f, 0.f, 0.f};

    stage(0, 0);
    stage(1, 1);
    int cbuf = 0;
    for (int t = 0; t < 26; ++t) {
        WAITV(3);
        __builtin_amdgcn_s_barrier();
        if (t + 2 < 27) stage(nxt3(nxt3(cbuf)), t + 2);
        COMPUTE(acc, cbuf);
        cbuf = nxt3(cbuf);
    }
    WAITV(0);
    __builtin_amdgcn_s_barrier();
    COMPUTE(acc, cbuf);

    // epilogue: bias + rational -> act (NHWC, packed short4)
    float cnm[3][6], cdn[3][4];
#pragma unroll
    for (int i = 0; i < 6; i++) { cnm[0][i] = num_r[i]; cnm[1][i] = num_g[i]; cnm[2][i] = num_b[i]; }
#pragma unroll
    for (int i = 0; i < 4; i++) { cdn[0][i] = fabsf(den_r[i]); cdn[1][i] = fabsf(den_g[i]); cdn[2][i] = fabsf(den_b[i]); }

    int abase[2];
#pragma unroll
    for (int n = 0; n < 2; ++n) {
        int pp = p0 + wave * 32 + n * 16 + (lane & 15);
        int n2 = pp / 784; int r2 = pp - n2 * 784;
        int oh2 = r2 / 28; int ow2 = r2 - oh2 * 28;
        abase[n] = ((n2 * 30 + oh2 + 1) * 30 + ow2 + 1) * 192;
    }
#pragma unroll
    for (int m = 0; m < 4; ++m) {
        int cob = co0 + m * 16 + ((lane >> 4) << 2);
        float res[2][4];
#pragma unroll
        for (int r = 0; r < 4; ++r) {
            float nm[6], dn[4];
            sel_coeffs((cob + r) % 3, cnm, cdn, nm, dn);
            float bv = bias1[cob + r];
#pragma unroll
            for (int n = 0; n < 2; ++n)
                res[n][r] = rational_eval(acc[m][n][r] + bv, nm, dn);
        }
#pragma unroll
        for (int n = 0; n < 2; ++n) {
            bf16x4 pk;
#pragma unroll
            for (int r = 0; r < 4; ++r) pk[r] = f2bf(res[n][r]);
            *(bf16x4*)&act[abase[n] + cob] = pk;
        }
    }
}

// ---------------- kernel B: shortcut(1x1 s2) + conv2(3x3 s1), both into one acc;
//                  + fused bias + rational -> out (NCHW f32) ----------------
extern "C" __global__ __launch_bounds__(256)
void convB_kernel(const short* __restrict__ act,
                  const short* __restrict__ xt,
                  const short* __restrict__ w2b,
                  const short* __restrict__ wsb,
                  const float* __restrict__ bias2s,
                  const float* __restrict__ num_r, const float* __restrict__ den_r,
                  const float* __restrict__ num_g, const float* __restrict__ den_g,
                  const float* __restrict__ num_b, const float* __restrict__ den_b,
                  float* __restrict__ outp)
{
    __shared__ short lA[3 * 2048];
    __shared__ short lB[3 * 4096];

    const int tid  = threadIdx.x;
    const int lane = tid & 63;
    const int wave = tid >> 6;
    const int lbid = swz_bid(blockIdx.x);
    const int co0  = (lbid % 3) * 64;
    const int p0   = (lbid / 3) * 128;

    const int swz8 = ((tid & 3) ^ ((tid >> 3) & 3)) * 8;
    const int arow = tid >> 2;
    int ab[2], xc0[2];
#pragma unroll
    for (int i = 0; i < 2; ++i) {
        int p = p0 + arow + i * 64;
        int n = p / 784; int pr = p - n * 784;
        int oh = pr / 28; int ow = pr - oh * 28;
        ab[i]  = ((n * 30 + oh) * 30 + ow) * 192 + swz8;                // padded act
        xc0[i] = ((n * 56 + 2 * oh) * 56 + 2 * ow) * 96 + swz8;        // xt center tap
    }
    const int aw2 = (co0 + arow) * 1728 + swz8;
    const int awS = (co0 + arow) * 96 + swz8;

    const int ksl = lane >> 4;
    int ard[4], brd[2];
#pragma unroll
    for (int m = 0; m < 4; ++m) ard[m] = lidx(m * 16 + (lane & 15), ksl);
#pragma unroll
    for (int n = 0; n < 2; ++n) brd[n] = lidx(wave * 32 + n * 16 + (lane & 15), ksl);

    // t 0..2: shortcut GEMM steps; t 3..56: conv2 steps
    auto stage = [&](int buf, int t) {
        if (t < 3) {
            gload16(&wsb[awS + t * 32], &lA[buf * 2048 + wave * 512]);
#pragma unroll
            for (int i = 0; i < 2; ++i)
                gload16(&xt[xc0[i] + t * 32], &lB[buf * 4096 + i * 2048 + wave * 512]);
        } else {
            int u = t - 3;
            int kpos = u / 6, cb = u - 6 * kpos;
            int kh = kpos / 3, kw = kpos - 3 * kh;
            int bko = (kh * 30 + kw) * 192 + cb * 32;
            gload16(&w2b[aw2 + kpos * 192 + cb * 32], &lA[buf * 2048 + wave * 512]);
#pragma unroll
            for (int i = 0; i < 2; ++i)
                gload16(&act[ab[i] + bko], &lB[buf * 4096 + i * 2048 + wave * 512]);
        }
    };

    f32x4 acc[4][2];
#pragma unroll
    for (int m = 0; m < 4; m++)
#pragma unroll
        for (int n = 0; n < 2; n++) acc[m][n] = (f32x4){0.f, 0.f, 0.f, 0.f};

    stage(0, 0);
    stage(1, 1);
    int cbuf = 0;
    for (int t = 0; t < 56; ++t) {
        WAITV(3);
        __builtin_amdgcn_s_barrier();
        if (t + 2 < 57) stage(nxt3(nxt3(cbuf)), t + 2);
        COMPUTE(acc, cbuf);
        cbuf = nxt3(cbuf);
    }
    WAITV(0);
    __builtin_amdgcn_s_barrier();
    COMPUTE(acc, cbuf);

    float cnm[3][6], cdn[3][4];
#pragma unroll
    for (int i = 0; i < 6; i++) { cnm[0][i] = num_r[i]; cnm[1][i] = num_g[i]; cnm[2][i] = num_b[i]; }
#pragma unroll
    for (int i = 0; i < 4; i++) { cdn[0][i] = fabsf(den_r[i]); cdn[1][i] = fabsf(den_g[i]); cdn[2][i] = fabsf(den_b[i]); }

    int obase[2];
#pragma unroll
    for (int n = 0; n < 2; ++n) {
        int pp = p0 + wave * 32 + n * 16 + (lane & 15);
        int n2 = pp / 784; int r2 = pp - n2 * 784;
        int oh2 = r2 / 28; int ow2 = r2 - oh2 * 28;
        obase[n] = n2 * (COUT * 784) + oh2 * 28 + ow2;
    }
#pragma unroll
    for (int m = 0; m < 4; ++m) {
        int cob = co0 + m * 16 + ((lane >> 4) << 2);
#pragma unroll
        for (int r = 0; r < 4; ++r) {
            float nm[6], dn[4];
            sel_coeffs((cob + r) % 3, cnm, cdn, nm, dn);
            float bv = bias2s[cob + r];
#pragma unroll
            for (int n = 0; n < 2; ++n) {
                int idx = obase[n] + (cob + r) * 784;
                outp[idx] = rational_eval(acc[m][n][r] + bv, nm, dn);
            }
        }
    }
}

// ---------------- launcher ----------------
extern "C" void kernel_launch(void* const* d_in, const int* in_sizes, int n_in,
                              void* d_out, int out_size, void* d_ws, size_t ws_size,
                              hipStream_t stream)
{
    const float* x      = (const float*)d_in[0];
    const float* w1     = (const float*)d_in[1];
    const float* gamma1 = (const float*)d_in[2];
    const float* beta1  = (const float*)d_in[3];
    const float* mean1  = (const float*)d_in[4];
    const float* var1   = (const float*)d_in[5];
    const float* num_r  = (const float*)d_in[6];
    const float* den_r  = (const float*)d_in[7];
    const float* num_g  = (const float*)d_in[8];
    const float* den_g  = (const float*)d_in[9];
    const float* num_b  = (const float*)d_in[10];
    const float* den_b  = (const float*)d_in[11];
    const float* w2     = (const float*)d_in[12];
    const float* gamma2 = (const float*)d_in[13];
    const float* beta2  = (const float*)d_in[14];
    const float* mean2  = (const float*)d_in[15];
    const float* var2   = (const float*)d_in[16];
    const float* wsc    = (const float*)d_in[17];
    const float* gammas = (const float*)d_in[18];
    const float* betas  = (const float*)d_in[19];
    const float* means  = (const float*)d_in[20];
    const float* vars_  = (const float*)d_in[21];

    char* base = (char*)d_ws;
    short* w1b  = (short*)(base + W1B_OFF);
    short* w2b  = (short*)(base + W2B_OFF);
    short* wsb  = (short*)(base + WSB_OFF);
    float* cs   = (float*)(base + CS_OFF);
    float* zb   = (float*)(base + ZB_OFF);
    short* xt   = (short*)(base + XT_OFF);
    short* act  = (short*)(base + ACT_OFF);
    float* outp = (float*)d_out;

    float* bias1  = cs + 576;
    float* bias2s = cs + 768;   // bias2 + biass fused

    prep_scales_kernel<<<1, 256, 0, stream>>>(gamma1, beta1, mean1, var1,
                                              gamma2, beta2, mean2, var2,
                                              gammas, betas, means, vars_, cs, zb);

    prep_w_kernel<<<(COUT * CIN * 9 + 255) / 256, 256, 0, stream>>>(w1, cs, w1b, CIN, 9, COUT * CIN * 9);
    prep_w_kernel<<<(COUT * COUT * 9 + 255) / 256, 256, 0, stream>>>(w2, cs + 192, w2b, COUT, 9, COUT * COUT * 9);
    prep_w_kernel<<<(COUT * CIN + 255) / 256, 256, 0, stream>>>(wsc, cs + 384, wsb, CIN, 1, COUT * CIN);

    {
        int tot_a = 64 * (2 * 30 + 2 * 28) * 192;
        ring_zero_kernel<<<(tot_a + 255) / 256, 256, 0, stream>>>(act, 30, 192, tot_a);
    }

    xpose_kernel<<<64 * 56, 256, 0, stream>>>(x, xt);

    convA_kernel<<<GRID, 256, 0, stream>>>(xt, w1b, (const short*)zb, bias1,
                                           num_r, den_r, num_g, den_g, num_b, den_b,
                                           act);

    convB_kernel<<<GRID, 256, 0, stream>>>(act, xt, w2b, wsb, bias2s,
                                           num_r, den_r, num_g, den_g, num_b, den_b,
                                           outp);
}